// Round 4
// baseline (255.420 us; speedup 1.0000x reference)
//
#include <hip/hip_runtime.h>
#include <stdint.h>

#define B_   32
#define CIN  256
#define COUT 512
#define A_   256
#define HW_  4096
#define NT   64
#define TILES 8

typedef short  short8  __attribute__((ext_vector_type(8)));
typedef float  float4_ __attribute__((ext_vector_type(4)));

__device__ __forceinline__ unsigned f2bf(float f) {
    unsigned u = __float_as_uint(f);
    u += 0x7FFFu + ((u >> 16) & 1u);   // RNE to bf16
    return u >> 16;
}
__device__ __forceinline__ float bf2f(unsigned h) {
    return __uint_as_float(h << 16);
}

// Kernel 0 (grid 64):
//  blocks 0..31  : zero P/T, ggbx[b][a] = g@Wg.T + bg + bx
//  blocks 32..63 : WxR fragment-linear repack of Wx (bf16)
//    entry e = ((w4*8+kk)*4+ai)*64 + lane  holds Wx[a=w4*64+ai*16+(lane&15)]
//                                               [k=kk*32+(lane>>4)*8 .. +7]
__global__ __launch_bounds__(256) void prep_kernel(
    const float* __restrict__ g, const float* __restrict__ Wg,
    const float* __restrict__ bg, const float* __restrict__ Wx,
    const float* __restrict__ bx,
    uint4* __restrict__ WxR, float* __restrict__ ggbx,
    float* __restrict__ P, float* __restrict__ T)
{
    int t = threadIdx.x;
    if (blockIdx.x >= 32) {
        int e = (blockIdx.x - 32) * 256 + t;
        int lane = e & 63, ai = (e >> 6) & 3, kk = (e >> 8) & 7, w = e >> 11;
        int a  = w * 64 + ai * 16 + (lane & 15);
        int kb = kk * 32 + (lane >> 4) * 8;
        const float4* s = (const float4*)(Wx + (size_t)a * 256 + kb);
        float4 u0 = s[0], u1 = s[1];
        uint4 pk;
        pk.x = f2bf(u0.x) | (f2bf(u0.y) << 16);
        pk.y = f2bf(u0.z) | (f2bf(u0.w) << 16);
        pk.z = f2bf(u1.x) | (f2bf(u1.y) << 16);
        pk.w = f2bf(u1.z) | (f2bf(u1.w) << 16);
        WxR[e] = pk;
        return;
    }
    int b = blockIdx.x;
    int i = b * 256 + t;
    P[i] = 0.f; T[i] = 0.f;

    __shared__ float gl[COUT];
    gl[t]       = g[b * COUT + t];
    gl[t + 256] = g[b * COUT + 256 + t];
    __syncthreads();

    float acc0 = bg[t] + bx[t], acc1 = 0.f;    // a = t, dual chain for ILP
    const float4* wr = (const float4*)(Wg + (size_t)t * COUT);
    #pragma unroll 8
    for (int co = 0; co < COUT / 4; co += 2) {
        float4 wv0 = wr[co],     gv0 = *(const float4*)&gl[co * 4];
        float4 wv1 = wr[co + 1], gv1 = *(const float4*)&gl[co * 4 + 4];
        acc0 += wv0.x * gv0.x + wv0.y * gv0.y + wv0.z * gv0.z + wv0.w * gv0.w;
        acc1 += wv1.x * gv1.x + wv1.y * gv1.y + wv1.z * gv1.z + wv1.w * gv1.w;
    }
    ggbx[b * 256 + t] = acc0 + acc1;
}

// Kernel 1: grid 256 (1 block/CU), 1024 threads = 16 waves (4 waves/SIMD).
// Each block owns (b, tg) = 8 consecutive n-tiles of 64. Per-tile pipeline:
//   issue loads(i+1) -> GEMM/epilogue/PT on buf[i&1] -> convert+write buf[(i+1)&1]
// Wave w owns a in [w*16, w*16+16): bfp = 8 short8 = 32 VGPR, so the whole
// kernel fits the 128-VGPR budget of 4 waves/SIMD (vs round 2's 2 waves/SIMD
// at 256 VGPR, which left phases latency-exposed). 4 waves/SIMD provide the
// intra-phase latency hiding that the barrier-locked schedule needs.
__global__ __launch_bounds__(1024)
__attribute__((amdgpu_waves_per_eu(4, 4)))
void attn_main(
    const float* __restrict__ x, const char* __restrict__ WxR,
    const float* __restrict__ ggbx, const float* __restrict__ Wf,
    const float* __restrict__ bfs,
    float* __restrict__ P, float* __restrict__ T, float* __restrict__ raw)
{
    // xT[buf][n][chunk]: chunk q (8 c as bf16x8, 16 B) XOR-swizzled by n&31
    __shared__ unsigned int xT[2][NT * 128];    // 2 x 32 KB
    __shared__ float att_part[16][NT];
    __shared__ float raw_l[NT];

    int bid = blockIdx.x;
    int b = bid >> 3, tg = bid & 7;
    int t = threadIdx.x, w = t >> 6, lane = t & 63;
    int quad = lane >> 4, l15 = lane & 15;

    const float* xb = x + (size_t)b * CIN * HW_ + tg * (TILES * NT);

    // ---- persistent A fragments (Wx): wave w -> a in [w*16, w*16+16) ----
    // WxR entry layout: byte = w4*32768 + kk*4096 + ai*1024 + lane*16,
    // with w4 = w>>2, ai = w&3.
    short8 bfp[8];
    {
        const char* wsl = WxR + (w >> 2) * 32768 + (w & 3) * 1024 + lane * 16;
        #pragma unroll
        for (int kk = 0; kk < 8; kk++)
            bfp[kk] = *(const short8*)(wsl + kk * 4096);
    }

    // per-lane gg+bx and Wf for a = w*16 + quad*4 + r  (r=0..3)
    float4_ ga4, wf4;
    {
        int a0 = w * 16 + quad * 4;
        ga4 = *(const float4_*)&ggbx[b * 256 + a0];
        wf4 = *(const float4_*)&Wf[a0];
    }

    // staging geometry: wave w stages c in [w*16, w*16+16), 4 rows/thread
    int n4 = l15 * 4;
    int cb = w * 16 + quad * 4;
    int qc = cb >> 3;                            // chunk = w*2 + (quad>>1)
    int hb = (cb & 4) << 1;                      // 0 or 8 bytes within chunk
    const float* xrow = xb + (size_t)cb * HW_ + n4;

    // ---- prologue: tile 0 ----
    float4_ v[4];
    #pragma unroll
    for (int j = 0; j < 4; j++)
        v[j] = *(const float4_*)(xrow + (size_t)j * HW_);
    #pragma unroll
    for (int r = 0; r < 4; r++) {
        uint2 pk;
        pk.x = f2bf(v[0][r]) | (f2bf(v[1][r]) << 16);
        pk.y = f2bf(v[2][r]) | (f2bf(v[3][r]) << 16);
        int n = n4 + r;
        *(uint2*)((char*)xT[0] + n * 512 + ((qc ^ (n & 31)) << 4) + hb) = pk;
    }

    float pp[4] = {0.f, 0.f, 0.f, 0.f};
    float tt[4] = {0.f, 0.f, 0.f, 0.f};
    int qpt   = (t & 63) >> 1;                   // P/T: logical chunk (8 c)
    int half  = (t & 1) * 8;                     // which 4 c (byte offset)
    int nbase = w * 4;                           // P/T: 4 n per wave

    __syncthreads();

    // unroll 1: keep one tile's register state live at a time
    #pragma unroll 1
    for (int it = 0; it < TILES; it++) {
        const unsigned int* xl = xT[it & 1];
        unsigned int* xw = xT[(it + 1) & 1];

        // issue next tile's loads; sched_barrier pins them at phase start
        if (it < TILES - 1) {
            const float* xn = xrow + (it + 1) * NT;
            #pragma unroll
            for (int j = 0; j < 4; j++)
                v[j] = *(const float4_*)(xn + (size_t)j * HW_);
        }
        __builtin_amdgcn_sched_barrier(0);

        // ---- K loop: pure LDS + MFMA; D[a][n] = Wx_frag x x_frag ----
        float4_ acc[4];
        #pragma unroll
        for (int mi = 0; mi < 4; mi++)
            acc[mi] = (float4_){0.f, 0.f, 0.f, 0.f};

        #pragma unroll
        for (int ks = 0; ks < 8; ks++) {
            int qk = ks * 4 + quad;
            short8 af[4];
            #pragma unroll
            for (int mi = 0; mi < 4; mi++) {
                int n = mi * 16 + l15;
                af[mi] = *(const short8*)&xl[n * 128 + ((qk ^ (n & 31)) << 2)];
            }
            #pragma unroll
            for (int mi = 0; mi < 4; mi++)
                acc[mi] = __builtin_amdgcn_mfma_f32_16x16x32_bf16(
                    bfp[ks], af[mi], acc[mi], 0, 0, 0);
        }

        // ---- epilogue: relu(D + gg + bx) * Wf; a-reduce in-lane over r
        // + 2 cross-quad shuffles. acc[mi][r] = D[a=w*16+quad*4+r][n=mi*16+l15]
        #pragma unroll
        for (int mi = 0; mi < 4; mi++) {
            float p = 0.f;
            #pragma unroll
            for (int r = 0; r < 4; r++) {
                float vv = fmaxf(acc[mi][r] + ga4[r], 0.f);
                p = fmaf(vv, wf4[r], p);
            }
            p += __shfl_xor(p, 16, 64);
            p += __shfl_xor(p, 32, 64);
            if (quad == 0) att_part[w][mi * 16 + l15] = p;
        }
        __syncthreads();

        if (t < NT) {
            float rv = bfs[0];
            #pragma unroll
            for (int g = 0; g < 16; g++) rv += att_part[g][t];
            raw[b * HW_ + (tg * TILES + it) * NT + t] = rv;
            raw_l[t] = rv;
        }
        __syncthreads();

        // ---- P/T accumulate: thread owns 4 c over 4 n, across all tiles ----
        #pragma unroll
        for (int i = 0; i < 4; i++) {
            int n = nbase + i;
            uint2 u = *(const uint2*)((const char*)xl + n * 512 + ((qpt ^ (n & 31)) << 4) + half);
            float rv = raw_l[n];
            float x0 = bf2f(u.x & 0xFFFFu), x1 = bf2f(u.x >> 16);
            float x2 = bf2f(u.y & 0xFFFFu), x3 = bf2f(u.y >> 16);
            pp[0] = fmaf(x0, rv, pp[0]); tt[0] += x0;
            pp[1] = fmaf(x1, rv, pp[1]); tt[1] += x1;
            pp[2] = fmaf(x2, rv, pp[2]); tt[2] += x2;
            pp[3] = fmaf(x3, rv, pp[3]); tt[3] += x3;
        }

        // ---- convert + write next tile into the other buffer ----
        if (it < TILES - 1) {
            #pragma unroll
            for (int r = 0; r < 4; r++) {
                uint2 pk;
                pk.x = f2bf(v[0][r]) | (f2bf(v[1][r]) << 16);
                pk.y = f2bf(v[2][r]) | (f2bf(v[3][r]) << 16);
                int n = n4 + r;
                *(uint2*)((char*)xw + n * 512 + ((qc ^ (n & 31)) << 4) + hb) = pk;
            }
        }
        __syncthreads();
    }

    // ---- block-level P/T reduce (scratch = xT[0]; tile 7 read xT[1]) ----
    {
        float* red = (float*)xT;                 // [16 waves][512]: P then T
        float4_* pr = (float4_*)(red + w * 512);
        float4_* tr = (float4_*)(red + w * 512 + 256);
        pr[lane] = (float4_){pp[0], pp[1], pp[2], pp[3]};
        tr[lane] = (float4_){tt[0], tt[1], tt[2], tt[3]};
        __syncthreads();
        if (t < 512) {
            int sel = t >> 8, cc = t & 255;      // 256 thr P, 256 thr T
            float s = 0.f;
            #pragma unroll
            for (int g = 0; g < 16; g++)
                s += red[g * 512 + sel * 256 + cc];
            atomicAdd((sel ? T : P) + b * 256 + cc, s);
        }
    }
}

// Kernel 2: per batch: min/sum over raw, write att output and pooled out
__global__ __launch_bounds__(256) void finalize_kernel(
    const float* __restrict__ raw, const float* __restrict__ P,
    const float* __restrict__ T, float* __restrict__ out)
{
    int b = blockIdx.x, t = threadIdx.x;
    const float* r = raw + (size_t)b * HW_;
    float v[16];
    float mn = 3.4e38f, sm = 0.f;
    #pragma unroll
    for (int i = 0; i < 16; i++) {
        v[i] = r[t + 256 * i];
        mn = fminf(mn, v[i]);
        sm += v[i];
    }
    #pragma unroll
    for (int off = 1; off < 64; off <<= 1) {
        mn = fminf(mn, __shfl_xor(mn, off, 64));
        sm += __shfl_xor(sm, off, 64);
    }
    __shared__ float smn[4], ssm[4];
    int w = t >> 6;
    if ((t & 63) == 0) { smn[w] = mn; ssm[w] = sm; }
    __syncthreads();
    mn = fminf(fminf(smn[0], smn[1]), fminf(smn[2], smn[3]));
    sm = (ssm[0] + ssm[1]) + (ssm[2] + ssm[3]);
    float S = sm - 4096.f * mn;                 // sum of (raw - min)
    float inv = 1.f / S;

    float* att = out + B_ * CIN + (size_t)b * HW_;
    #pragma unroll
    for (int i = 0; i < 16; i++) att[t + 256 * i] = (v[i] - mn) * inv;

    int ic = b * 256 + t;
    out[ic] = (P[ic] - mn * T[ic]) * inv;
}

extern "C" void kernel_launch(void* const* d_in, const int* in_sizes, int n_in,
                              void* d_out, int out_size, void* d_ws, size_t ws_size,
                              hipStream_t stream)
{
    const float* x   = (const float*)d_in[0];
    const float* g   = (const float*)d_in[1];
    const float* Wg  = (const float*)d_in[2];
    const float* bg  = (const float*)d_in[3];
    const float* Wx  = (const float*)d_in[4];
    const float* bx  = (const float*)d_in[5];
    const float* Wf  = (const float*)d_in[6];
    const float* bf  = (const float*)d_in[7];
    float* out = (float*)d_out;

    char* wsb = (char*)d_ws;
    uint4* WxR  = (uint4*)wsb;                            // 128 KB
    float* ggbx = (float*)(wsb + 131072);                 // 32 KB
    float* P    = ggbx + 8192;                            // 32 KB
    float* T    = P + 8192;                               // 32 KB
    float* raw  = T + 8192;                               // 512 KB

    prep_kernel<<<64, 256, 0, stream>>>(g, Wg, bg, Wx, bx, WxR, ggbx, P, T);
    attn_main<<<256, 1024, 0, stream>>>(x, (const char*)WxR, ggbx, Wf, bf, P, T, raw);
    finalize_kernel<<<32, 256, 0, stream>>>(raw, P, T, out);
}